// Round 6
// baseline (281.816 us; speedup 1.0000x reference)
//
#include <hip/hip_runtime.h>
#include <math.h>

// Attend (talking-heads, causal) for B=4,H=16,N=1024,D=64 fp32.
// Round 6: two-pass chunked structure (r5) with the byte streams shrunk:
//  - bias pre-converted to bf16 (triangle only) -> halves the dominant fetch
//  - attend_o chunk width 256 (4 chunks) -> atomic out-traffic halved
//  - attend_l 3 WGs/CU (48KB LDS, launch_bounds(512,6))
//  - heavy-first dispatch order (r descending)

#define NB 4
#define NH 16
#define NS 1024
#define ND 64
#define IT 16
#define JT 64
#define CWL 128    // attend_l chunk width (8 chunks)
#define CWO 256    // attend_o chunk width (4 chunks)
#define HPAD 24    // dots [c=(i,j)][24] bf16: 48B rows, 16B-aligned

typedef __bf16 bf16x8 __attribute__((ext_vector_type(8)));
typedef __bf16 bf16x4 __attribute__((ext_vector_type(4)));
typedef float  f32x4  __attribute__((ext_vector_type(4)));

__device__ __forceinline__ f32x4 fzero4() {
  f32x4 z; z[0] = 0.f; z[1] = 0.f; z[2] = 0.f; z[3] = 0.f; return z;
}

// heavy-first decodes: r descending with bid; c rotated per r for balance.
__device__ __forceinline__ bool decode_l(int bid, int& b, int& i0, int& jlo,
                                         int& jhi, int& nsteps) {
  const int r = 63 - (bid >> 5);
  b = (bid >> 3) & 3;
  const int c = ((bid & 7) + r) & 7;
  i0 = r * IT;
  jlo = c * CWL;
  if (jlo > i0 + IT - 1) return false;
  jhi = min(jlo + CWL, i0 + IT);
  nsteps = (jhi - jlo + JT - 1) / JT;
  return true;
}

__device__ __forceinline__ bool decode_o(int bid, int& b, int& i0, int& jlo,
                                         int& jhi, int& nsteps) {
  const int r = 63 - (bid >> 4);
  b = (bid >> 2) & 3;
  const int c = ((bid & 3) + r) & 3;
  i0 = r * IT;
  jlo = c * CWO;
  if (jlo > i0 + IT - 1) return false;
  jhi = min(jlo + CWO, i0 + IT);
  nsteps = (jhi - jlo + JT - 1) / JT;
  return true;
}

// ---------------- prep: Qb(1/8), Kb, VT [b,h,d,j], BiasB (bf16 triangle) ----------------
#define QK_BLKS   8192   // 2*nelem/4/256
#define VT_BLKS   1024   // 64 bh * 16 jtiles
#define BIAS_BLKS 16384  // 16.8M/4/256

__global__ __launch_bounds__(256)
void prep(const float* __restrict__ Q, const float* __restrict__ K,
          const float* __restrict__ V, const float* __restrict__ Bg,
          __bf16* __restrict__ Qb, __bf16* __restrict__ Kb,
          __bf16* __restrict__ VT, __bf16* __restrict__ BiasB) {
  __shared__ float tile[64][65];
  const int bid = blockIdx.x;
  const int t = threadIdx.x;
  if (bid < QK_BLKS) {
    const size_t nq4 = (size_t)NB * NH * NS * ND / 4;
    size_t idx = (size_t)bid * 256 + t;
    if (idx < nq4) {
      float4 x = reinterpret_cast<const float4*>(Q)[idx];
      bf16x4 o;
      o[0] = (__bf16)(x.x * 0.125f); o[1] = (__bf16)(x.y * 0.125f);
      o[2] = (__bf16)(x.z * 0.125f); o[3] = (__bf16)(x.w * 0.125f);
      reinterpret_cast<bf16x4*>(Qb)[idx] = o;
    } else {
      idx -= nq4;
      float4 x = reinterpret_cast<const float4*>(K)[idx];
      bf16x4 o;
      o[0] = (__bf16)x.x; o[1] = (__bf16)x.y; o[2] = (__bf16)x.z; o[3] = (__bf16)x.w;
      reinterpret_cast<bf16x4*>(Kb)[idx] = o;
    }
  } else if (bid < QK_BLKS + VT_BLKS) {
    const int vb = bid - QK_BLKS;
    const int bh = vb >> 4;
    const int j0 = (vb & 15) * 64;
    const float* vp = V + ((size_t)bh * NS + j0) * ND;
#pragma unroll
    for (int rep = 0; rep < 4; ++rep) {
      int lin = rep * 256 + t;
      int jj = lin >> 4;
      int dd = (lin & 15) * 4;
      float4 x = *reinterpret_cast<const float4*>(vp + (size_t)jj * ND + dd);
      tile[jj][dd] = x.x; tile[jj][dd + 1] = x.y;
      tile[jj][dd + 2] = x.z; tile[jj][dd + 3] = x.w;
    }
    __syncthreads();
    __bf16* op = VT + (size_t)bh * ND * NS + j0;
#pragma unroll
    for (int rep = 0; rep < 16; ++rep) {
      int lin = rep * 256 + t;
      int d = lin >> 6;
      int jj = lin & 63;
      op[(size_t)d * NS + jj] = (__bf16)tile[jj][d];
    }
  } else {
    // bias: convert lower-triangle float4 lanes only
    size_t idx = (size_t)(bid - QK_BLKS - VT_BLKS) * 256 + t;   // float4 idx
    const int row = (int)(idx >> 8);       // g*1024 + i
    const int i   = row & 1023;
    const int j4  = (int)(idx & 255);
    if (j4 * 4 <= i) {
      float4 x = reinterpret_cast<const float4*>(Bg)[idx];
      bf16x4 o;
      o[0] = (__bf16)x.x; o[1] = (__bf16)x.y; o[2] = (__bf16)x.z; o[3] = (__bf16)x.w;
      reinterpret_cast<bf16x4*>(BiasB)[idx] = o;
    }
  }
}

// ---------------- kernel 1: partial L ----------------
template <bool WS>
__global__ __launch_bounds__(512, 6)
void attend_l(const float* __restrict__ Qg, const float* __restrict__ Kg,
              const float* __restrict__ Bg, const float* __restrict__ Wpre,
              const __bf16* __restrict__ Qb, const __bf16* __restrict__ Kb,
              const __bf16* __restrict__ BiasB, float* __restrict__ Lws)
{
  int b, i0, jlo, jhi, nsteps;
  if (!decode_l(blockIdx.x, b, i0, jlo, jhi, nsteps)) return;

  const int tid = threadIdx.x;
  const int w = tid >> 6;          // wave 0..7
  const int lane = tid & 63;
  const int lr = lane & 15;
  const int lg = lane >> 4;

  __shared__ __align__(16) __bf16 dots[IT * JT * HPAD];  // 48KB

  bf16x8 wpreF;
#pragma unroll
  for (int e = 0; e < 8; ++e) wpreF[e] = (__bf16)0.f;
  if (lg < 2) {
#pragma unroll
    for (int e = 0; e < 8; ++e) wpreF[e] = (__bf16)Wpre[lr * NH + lg * 8 + e];
  }

  bf16x8 qF[2][2];
#pragma unroll
  for (int hh = 0; hh < 2; ++hh) {
    const int h = w + hh * 8;
    if constexpr (WS) {
      const __bf16* qp = Qb + ((size_t)(b * NH + h) * NS + i0 + lr) * ND + lg * 8;
      qF[hh][0] = *reinterpret_cast<const bf16x8*>(qp);
      qF[hh][1] = *reinterpret_cast<const bf16x8*>(qp + 32);
    } else {
      const float* qp = Qg + ((size_t)(b * NH + h) * NS + i0 + lr) * ND + lg * 8;
#pragma unroll
      for (int ks = 0; ks < 2; ++ks) {
        float4 x = *reinterpret_cast<const float4*>(qp + ks * 32);
        float4 y = *reinterpret_cast<const float4*>(qp + ks * 32 + 4);
        bf16x8 f;
        f[0] = (__bf16)(x.x * 0.125f); f[1] = (__bf16)(x.y * 0.125f);
        f[2] = (__bf16)(x.z * 0.125f); f[3] = (__bf16)(x.w * 0.125f);
        f[4] = (__bf16)(y.x * 0.125f); f[5] = (__bf16)(y.y * 0.125f);
        f[6] = (__bf16)(y.z * 0.125f); f[7] = (__bf16)(y.w * 0.125f);
        qF[hh][ks] = f;
      }
    }
  }

  float Lp[2][4];
#pragma unroll
  for (int ii = 0; ii < 2; ++ii)
#pragma unroll
    for (int rr = 0; rr < 4; ++rr) Lp[ii][rr] = 0.f;

  for (int s = 0; s < nsteps; ++s) {
    const int j0 = jlo + s * JT;
    float br[2][4][4];
#pragma unroll
    for (int ii = 0; ii < 2; ++ii) {
      const int gi = i0 + w + ii * 8;
#pragma unroll
      for (int qq = 0; qq < 4; ++qq)
#pragma unroll
        for (int rr = 0; rr < 4; ++rr) {
          const size_t idx = ((size_t)(lg * 4 + rr) * NS + gi) * NS + j0 + qq * 16 + lr;
          if constexpr (WS) br[ii][qq][rr] = (float)BiasB[idx];
          else              br[ii][qq][rr] = Bg[idx];
        }
    }
    if (s) __syncthreads();
#pragma unroll
    for (int hh = 0; hh < 2; ++hh) {
      const int h = w + hh * 8;
#pragma unroll
      for (int jb = 0; jb < 4; ++jb) {
        f32x4 acc = fzero4();
#pragma unroll
        for (int ks = 0; ks < 2; ++ks) {
          bf16x8 kf;
          if constexpr (WS) {
            kf = *reinterpret_cast<const bf16x8*>(
                Kb + ((size_t)(b * NH + h) * NS + j0 + jb * 16 + lr) * ND + ks * 32 + lg * 8);
          } else {
            const float* kp = Kg + ((size_t)(b * NH + h) * NS + j0 + jb * 16 + lr) * ND + ks * 32 + lg * 8;
            float4 x = *reinterpret_cast<const float4*>(kp);
            float4 y = *reinterpret_cast<const float4*>(kp + 4);
            kf[0] = (__bf16)x.x; kf[1] = (__bf16)x.y; kf[2] = (__bf16)x.z; kf[3] = (__bf16)x.w;
            kf[4] = (__bf16)y.x; kf[5] = (__bf16)y.y; kf[6] = (__bf16)y.z; kf[7] = (__bf16)y.w;
          }
          acc = __builtin_amdgcn_mfma_f32_16x16x32_bf16(qF[hh][ks], kf, acc, 0, 0, 0);
        }
#pragma unroll
        for (int rr = 0; rr < 4; ++rr)
          dots[((lg * 4 + rr) * JT + jb * 16 + lr) * HPAD + h] = (__bf16)acc[rr];
      }
    }
    __syncthreads();
#pragma unroll
    for (int ii = 0; ii < 2; ++ii) {
      const int i = w + ii * 8;
      const int gi = i0 + i;
#pragma unroll
      for (int qq = 0; qq < 4; ++qq) {
        bf16x8 bfr;
#pragma unroll
        for (int e = 0; e < 8; ++e) bfr[e] = (__bf16)0.f;
        if (lg < 2)
          bfr = *reinterpret_cast<const bf16x8*>(&dots[(i * JT + qq * 16 + lr) * HPAD + lg * 8]);
        f32x4 s1 = __builtin_amdgcn_mfma_f32_16x16x32_bf16(wpreF, bfr, fzero4(), 0, 0, 0);
        const int gj = j0 + qq * 16 + lr;
#pragma unroll
        for (int rr = 0; rr < 4; ++rr)
          if (gj <= gi) Lp[ii][rr] += __expf(s1[rr] + br[ii][qq][rr]);
      }
    }
  }

#pragma unroll
  for (int ii = 0; ii < 2; ++ii)
#pragma unroll
    for (int rr = 0; rr < 4; ++rr) {
      float v = Lp[ii][rr];
      v += __shfl_xor(v, 1, 64);
      v += __shfl_xor(v, 2, 64);
      v += __shfl_xor(v, 4, 64);
      v += __shfl_xor(v, 8, 64);
      if (lr == 0)
        atomicAdd(&Lws[(size_t)(b * NH + lg * 4 + rr) * NS + i0 + w + ii * 8], v);
    }
}

// ---------------- kernel 2: partial out ----------------
template <bool WS>
__global__ __launch_bounds__(512, 4)
void attend_o(const float* __restrict__ Qg, const float* __restrict__ Kg,
              const float* __restrict__ Vg, const float* __restrict__ Bg,
              const float* __restrict__ Wpre, const float* __restrict__ Wpost,
              const __bf16* __restrict__ Qb, const __bf16* __restrict__ Kb,
              const __bf16* __restrict__ VTb, const __bf16* __restrict__ BiasB,
              const float* __restrict__ Lws, float* __restrict__ Og)
{
  int b, i0, jlo, jhi, nsteps;
  if (!decode_o(blockIdx.x, b, i0, jlo, jhi, nsteps)) return;

  const int tid = threadIdx.x;
  const int w = tid >> 6;
  const int lane = tid & 63;
  const int lr = lane & 15;
  const int lg = lane >> 4;

  __shared__ __align__(16) __bf16 dots[IT * JT * HPAD];  // 48KB (dots, E' in place)
  __shared__ __align__(16) __bf16 sbP2[256 * 64];        // 32KB, 16B-unit XOR swizzle

  bf16x8 wpreF, wpostF;
#pragma unroll
  for (int e = 0; e < 8; ++e) { wpreF[e] = (__bf16)0.f; wpostF[e] = (__bf16)0.f; }
  if (lg < 2) {
#pragma unroll
    for (int e = 0; e < 8; ++e) {
      wpreF[e]  = (__bf16)Wpre [lr * NH + lg * 8 + e];
      wpostF[e] = (__bf16)Wpost[lr * NH + lg * 8 + e];
    }
  }

  bf16x8 qF[2][2];
#pragma unroll
  for (int hh = 0; hh < 2; ++hh) {
    const int h = w + hh * 8;
    if constexpr (WS) {
      const __bf16* qp = Qb + ((size_t)(b * NH + h) * NS + i0 + lr) * ND + lg * 8;
      qF[hh][0] = *reinterpret_cast<const bf16x8*>(qp);
      qF[hh][1] = *reinterpret_cast<const bf16x8*>(qp + 32);
    } else {
      const float* qp = Qg + ((size_t)(b * NH + h) * NS + i0 + lr) * ND + lg * 8;
#pragma unroll
      for (int ks = 0; ks < 2; ++ks) {
        float4 x = *reinterpret_cast<const float4*>(qp + ks * 32);
        float4 y = *reinterpret_cast<const float4*>(qp + ks * 32 + 4);
        bf16x8 f;
        f[0] = (__bf16)(x.x * 0.125f); f[1] = (__bf16)(x.y * 0.125f);
        f[2] = (__bf16)(x.z * 0.125f); f[3] = (__bf16)(x.w * 0.125f);
        f[4] = (__bf16)(y.x * 0.125f); f[5] = (__bf16)(y.y * 0.125f);
        f[6] = (__bf16)(y.z * 0.125f); f[7] = (__bf16)(y.w * 0.125f);
        qF[hh][ks] = f;
      }
    }
  }

  float linv[2][4];
#pragma unroll
  for (int ii = 0; ii < 2; ++ii)
#pragma unroll
    for (int rr = 0; rr < 4; ++rr)
      linv[ii][rr] = 1.f / Lws[(size_t)(b * NH + lg * 4 + rr) * NS + i0 + w + ii * 8];

  f32x4 oacc[2][4];
#pragma unroll
  for (int hh = 0; hh < 2; ++hh)
#pragma unroll
    for (int db = 0; db < 4; ++db) oacc[hh][db] = fzero4();

  auto pv_phase = [&](int j0) {
#pragma unroll
    for (int hh = 0; hh < 2; ++hh) {
      const int g = w + hh * 8;
      const int row = g * IT + lr;
      const int sw = row & 7;
      bf16x8 pf0 = *reinterpret_cast<const bf16x8*>(&sbP2[row * 64 + ((lg ^ sw) << 3)]);
      bf16x8 pf1 = *reinterpret_cast<const bf16x8*>(&sbP2[row * 64 + (((4 + lg) ^ sw) << 3)]);
#pragma unroll
      for (int db = 0; db < 4; ++db) {
        bf16x8 vf0, vf1;
        if constexpr (WS) {
          const __bf16* vp = VTb + ((size_t)(b * NH + g) * ND + db * 16 + lr) * NS + j0 + lg * 8;
          vf0 = *reinterpret_cast<const bf16x8*>(vp);
          vf1 = *reinterpret_cast<const bf16x8*>(vp + 32);
        } else {
          const float* vb = Vg + (size_t)(b * NH + g) * NS * ND;
#pragma unroll
          for (int e = 0; e < 8; ++e) {
            vf0[e] = (__bf16)vb[(size_t)(j0 + lg * 8 + e) * ND + db * 16 + lr];
            vf1[e] = (__bf16)vb[(size_t)(j0 + 32 + lg * 8 + e) * ND + db * 16 + lr];
          }
        }
        oacc[hh][db] = __builtin_amdgcn_mfma_f32_16x16x32_bf16(pf0, vf0, oacc[hh][db], 0, 0, 0);
        oacc[hh][db] = __builtin_amdgcn_mfma_f32_16x16x32_bf16(pf1, vf1, oacc[hh][db], 0, 0, 0);
      }
    }
  };

  for (int s = 0; s < nsteps; ++s) {
    const int j0 = jlo + s * JT;
    float br[2][4][4];
#pragma unroll
    for (int ii = 0; ii < 2; ++ii) {
      const int gi = i0 + w + ii * 8;
#pragma unroll
      for (int qq = 0; qq < 4; ++qq)
#pragma unroll
        for (int rr = 0; rr < 4; ++rr) {
          const size_t idx = ((size_t)(lg * 4 + rr) * NS + gi) * NS + j0 + qq * 16 + lr;
          if constexpr (WS) br[ii][qq][rr] = (float)BiasB[idx];
          else              br[ii][qq][rr] = Bg[idx];
        }
    }

    // ---- phase1: PV(s-1) || QK(s) ----
    if (s > 0) pv_phase(j0 - JT);
#pragma unroll
    for (int hh = 0; hh < 2; ++hh) {
      const int h = w + hh * 8;
#pragma unroll
      for (int jb = 0; jb < 4; ++jb) {
        f32x4 acc = fzero4();
#pragma unroll
        for (int ks = 0; ks < 2; ++ks) {
          bf16x8 kf;
          if constexpr (WS) {
            kf = *reinterpret_cast<const bf16x8*>(
                Kb + ((size_t)(b * NH + h) * NS + j0 + jb * 16 + lr) * ND + ks * 32 + lg * 8);
          } else {
            const float* kp = Kg + ((size_t)(b * NH + h) * NS + j0 + jb * 16 + lr) * ND + ks * 32 + lg * 8;
            float4 x = *reinterpret_cast<const float4*>(kp);
            float4 y = *reinterpret_cast<const float4*>(kp + 4);
            kf[0] = (__bf16)x.x; kf[1] = (__bf16)x.y; kf[2] = (__bf16)x.z; kf[3] = (__bf16)x.w;
            kf[4] = (__bf16)y.x; kf[5] = (__bf16)y.y; kf[6] = (__bf16)y.z; kf[7] = (__bf16)y.w;
          }
          acc = __builtin_amdgcn_mfma_f32_16x16x32_bf16(qF[hh][ks], kf, acc, 0, 0, 0);
        }
#pragma unroll
        for (int rr = 0; rr < 4; ++rr)
          dots[((lg * 4 + rr) * JT + jb * 16 + lr) * HPAD + h] = (__bf16)acc[rr];
      }
    }
    __syncthreads();

    // ---- phase2: mix1 (E' in place, own rows) + mix2 -> swizzled P2 ----
#pragma unroll
    for (int ii = 0; ii < 2; ++ii) {
      const int i = w + ii * 8;
      const int gi = i0 + i;
#pragma unroll
      for (int qq = 0; qq < 4; ++qq) {
        bf16x8 bfr;
#pragma unroll
        for (int e = 0; e < 8; ++e) bfr[e] = (__bf16)0.f;
        if (lg < 2)
          bfr = *reinterpret_cast<const bf16x8*>(&dots[(i * JT + qq * 16 + lr) * HPAD + lg * 8]);
        f32x4 s1 = __builtin_amdgcn_mfma_f32_16x16x32_bf16(wpreF, bfr, fzero4(), 0, 0, 0);
        const int gj = j0 + qq * 16 + lr;
        const int cc = i * JT + qq * 16 + lr;
#pragma unroll
        for (int rr = 0; rr < 4; ++rr) {
          float ev = 0.f;
          if (gj <= gi) ev = __expf(s1[rr] + br[ii][qq][rr]) * linv[ii][rr];
          dots[cc * HPAD + lg * 4 + rr] = (__bf16)ev;
        }
      }
#pragma unroll
      for (int qq = 0; qq < 4; ++qq) {
        bf16x8 efr;
#pragma unroll
        for (int e = 0; e < 8; ++e) efr[e] = (__bf16)0.f;
        if (lg < 2)
          efr = *reinterpret_cast<const bf16x8*>(&dots[(i * JT + qq * 16 + lr) * HPAD + lg * 8]);
        f32x4 p2 = __builtin_amdgcn_mfma_f32_16x16x32_bf16(wpostF, efr, fzero4(), 0, 0, 0);
        const int u = (qq * 16 + lr) >> 3;
#pragma unroll
        for (int rr = 0; rr < 4; ++rr) {
          const int row = (lg * 4 + rr) * IT + i;
          sbP2[row * 64 + ((u ^ (i & 7)) << 3) + (lr & 7)] = (__bf16)p2[rr];
        }
      }
    }
    __syncthreads();
  }
  pv_phase(jlo + (nsteps - 1) * JT);

#pragma unroll
  for (int hh = 0; hh < 2; ++hh) {
    const int g = w + hh * 8;
    float* ob = Og + ((size_t)(b * NH + g) * NS + i0) * ND;
#pragma unroll
    for (int db = 0; db < 4; ++db)
#pragma unroll
      for (int rr = 0; rr < 4; ++rr)
        atomicAdd(&ob[(size_t)(lg * 4 + rr) * ND + db * 16 + lr], oacc[hh][db][rr]);
  }
}

extern "C" void kernel_launch(void* const* d_in, const int* in_sizes, int n_in,
                              void* d_out, int out_size, void* d_ws, size_t ws_size,
                              hipStream_t stream) {
  const float* Q     = (const float*)d_in[0];
  const float* K     = (const float*)d_in[1];
  const float* V     = (const float*)d_in[2];
  const float* BIAS  = (const float*)d_in[3];
  const float* WPRE  = (const float*)d_in[4];
  const float* WPOST = (const float*)d_in[5];
  float* OUT = (float*)d_out;
  (void)in_sizes; (void)n_in;

  const size_t nelem  = (size_t)NB * NH * NS * ND;              // 4.19M
  const size_t nbias  = (size_t)NH * NS * NS;                   // 16.8M
  const size_t lbytes = (size_t)NB * NH * NS * sizeof(float);   // 256KB
  const size_t need   = lbytes + (3 * nelem + nbias) * sizeof(__bf16);  // ~59MB

  float* Lws = (float*)d_ws;
  hipMemsetAsync(d_ws, 0, lbytes, stream);
  hipMemsetAsync(d_out, 0, (size_t)out_size * sizeof(float), stream);

  if (ws_size >= need) {
    __bf16* Qb = (__bf16*)((char*)d_ws + lbytes);
    __bf16* Kb = Qb + nelem;
    __bf16* VT = Kb + nelem;
    __bf16* BB = VT + nelem;
    hipLaunchKernelGGL(prep, dim3(QK_BLKS + VT_BLKS + BIAS_BLKS), dim3(256), 0, stream,
                       Q, K, V, BIAS, Qb, Kb, VT, BB);
    hipLaunchKernelGGL((attend_l<true>), dim3(2048), dim3(512), 0, stream,
                       Q, K, BIAS, WPRE, Qb, Kb, BB, Lws);
    hipLaunchKernelGGL((attend_o<true>), dim3(1024), dim3(512), 0, stream,
                       Q, K, V, BIAS, WPRE, WPOST, Qb, Kb, VT, BB, Lws, OUT);
  } else {
    hipLaunchKernelGGL((attend_l<false>), dim3(2048), dim3(512), 0, stream,
                       Q, K, BIAS, WPRE, (const __bf16*)nullptr,
                       (const __bf16*)nullptr, (const __bf16*)nullptr, Lws);
    hipLaunchKernelGGL((attend_o<false>), dim3(1024), dim3(512), 0, stream,
                       Q, K, V, BIAS, WPRE, WPOST, (const __bf16*)nullptr,
                       (const __bf16*)nullptr, (const __bf16*)nullptr,
                       (const __bf16*)nullptr, Lws, OUT);
  }
}